// Round 14
// baseline (163.137 us; speedup 1.0000x reference)
//
#include <hip/hip_runtime.h>
#include <math.h>

#define D_MODEL 1024
#define NUM_HEADS 16
#define HEAD_DIM 64
#define EPS 1e-8f
#define B_SZ 2
#define T_SZ 2048
#define KEXP 2048          // expanded K (hi+lo interleaved per 32-chunk)

typedef unsigned short ushort_t;
typedef __attribute__((ext_vector_type(8))) short bf16x8;
typedef __attribute__((ext_vector_type(4))) float f32x4;

// float -> bf16 round-to-nearest-even
__device__ __forceinline__ ushort_t f2bf(float f) {
    unsigned u = __float_as_uint(f);
    unsigned r = (u + 0x7FFFu + ((u >> 16) & 1u)) >> 16;
    return (ushort_t)r;
}
__device__ __forceinline__ float bf2f(ushort_t h) {
    return __uint_as_float(((unsigned)h) << 16);
}
__device__ __forceinline__ float frcp(float x) { return __builtin_amdgcn_rcpf(x); }

__device__ __forceinline__ void gload_lds16(const ushort_t* g, ushort_t* l) {
    __builtin_amdgcn_global_load_lds(
        (const __attribute__((address_space(1))) unsigned int*)g,
        (__attribute__((address_space(3))) unsigned int*)l, 16, 0, 0);
}

// ---------------------------------------------------------------------------
// Expand fp32 [rows][1024] -> bf16 [rows][2048]; per 32-k chunk: 32 hi, 32 lo.
// ---------------------------------------------------------------------------
__global__ __launch_bounds__(256) void expand7(
    const float* q, const float* k, const float* v,
    const float* wq, const float* wk, const float* wv, const float* wo,
    ushort_t* qe, ushort_t* ke, ushort_t* ve,
    ushort_t* wqe, ushort_t* wke, ushort_t* wve, ushort_t* woe)
{
    const float* in; ushort_t* out; int rows;
    switch (blockIdx.z) {
        case 0: in = q;  out = qe;  rows = 4096; break;
        case 1: in = k;  out = ke;  rows = 4096; break;
        case 2: in = v;  out = ve;  rows = 4096; break;
        case 3: in = wq; out = wqe; rows = 1024; break;
        case 4: in = wk; out = wke; rows = 1024; break;
        case 5: in = wv; out = wve; rows = 1024; break;
        default: in = wo; out = woe; rows = 1024; break;
    }
    const int gid = blockIdx.x * 256 + threadIdx.x;
    const int total = rows * 1024;
    for (int e = gid * 8; e < total; e += 1024 * 256 * 8) {
        const int row = e >> 10;
        const int kk = e & 1023;

        float x[8];
        *(float4*)&x[0] = *(const float4*)&in[(size_t)row * 1024 + kk];
        *(float4*)&x[4] = *(const float4*)&in[(size_t)row * 1024 + kk + 4];

        union { ushort_t s[8]; uint4 u; } hi, lo;
        #pragma unroll
        for (int i = 0; i < 8; ++i) {
            ushort_t h = f2bf(x[i]);
            hi.s[i] = h;
            lo.s[i] = f2bf(x[i] - bf2f(h));
        }
        ushort_t* dst = out + (size_t)row * KEXP + (kk >> 5) * 64 + (kk & 31);
        *(uint4*)dst        = hi.u;
        *(uint4*)(dst + 32) = lo.u;
    }
}

// ---------------------------------------------------------------------------
// Split-bf16 GEMM, dbuf + counted vmcnt (stage-C-proven structure: NLD=6,
// 48 KB LDS, 3 blocks/CU), generalized to 3 triples via blockIdx.z.
// BM=128, BN=64, 4 waves (4x1), 16x16x32, 3 MFMAs per fragment pair.
// LDS rows 128B, XOR slot-swizzle s^(row&7); bijective XCD swizzle.
// ---------------------------------------------------------------------------
template<int BN, int WAVES_M, int WAVES_N>
__global__ __launch_bounds__(256) void gemm_db3(
    const ushort_t* A0, const ushort_t* B0, float* C0,
    const ushort_t* A1, const ushort_t* B1, float* C1,
    const ushort_t* A2, const ushort_t* B2, float* C2,
    int M, int N)
{
    constexpr int BM = 128;
    constexpr int WAVE_M = BM / WAVES_M;
    constexpr int WAVE_N = BN / WAVES_N;
    constexpr int FM = WAVE_M / 16;
    constexpr int FN = WAVE_N / 16;
    constexpr int NLD = BM / 32 + BN / 32;

    const int gx = gridDim.x, gy = gridDim.y;
    const int nwg = gx * gy * gridDim.z;
    const int lid = blockIdx.x + gx * (blockIdx.y + gy * blockIdx.z);
    const int cpx = nwg >> 3;
    const int swz = (lid & 7) * cpx + (lid >> 3);
    const int bz  = swz / (gx * gy);
    const int rem = swz - bz * gx * gy;
    const int by  = rem / gx;
    const int bx  = rem - by * gx;

    const ushort_t* Ae; const ushort_t* Be; float* C;
    if (bz == 0)      { Ae = A0; Be = B0; C = C0; }
    else if (bz == 1) { Ae = A1; Be = B1; C = C1; }
    else              { Ae = A2; Be = B2; C = C2; }

    __shared__ __align__(16) ushort_t As0[BM * 64];
    __shared__ __align__(16) ushort_t As1[BM * 64];
    __shared__ __align__(16) ushort_t Bs0[BN * 64];
    __shared__ __align__(16) ushort_t Bs1[BN * 64];

    const int tid = threadIdx.x;
    const int bm = by * BM;
    const int bn = bx * BN;

    const int rr = tid >> 3;
    const int p  = tid & 7;

    const int wid  = tid >> 6;
    const int wm   = wid / WAVES_N;
    const int wn   = wid % WAVES_N;
    const int lane = tid & 63;
    const int lrow = lane & 15;
    const int lk   = lane >> 4;

    f32x4 acc[FM][FN] = {};

    auto stage = [&](ushort_t* AsP, ushort_t* BsP, int ks) {
        const int kb = ks * 64;
        #pragma unroll
        for (int r = 0; r < BM / 32; ++r) {
            const int row = r * 32 + rr;
            const int s = p ^ (row & 7);
            gload_lds16(Ae + (size_t)(bm + row) * KEXP + kb + s * 8,
                        &AsP[row * 64 + p * 8]);
        }
        #pragma unroll
        for (int r = 0; r < BN / 32; ++r) {
            const int row = r * 32 + rr;
            const int s = p ^ (row & 7);
            gload_lds16(Be + (size_t)(bn + row) * KEXP + kb + s * 8,
                        &BsP[row * 64 + p * 8]);
        }
    };

    auto compute = [&](const ushort_t* AsP, const ushort_t* BsP) {
        bf16x8 ah[FM], al[FM], bh[FN], bl[FN];
        #pragma unroll
        for (int m = 0; m < FM; ++m) {
            const int row = wm * WAVE_M + m * 16 + lrow;
            const int x = row & 7;
            ah[m] = *(const bf16x8*)&AsP[row * 64 + ((lk)     ^ x) * 8];
            al[m] = *(const bf16x8*)&AsP[row * 64 + ((lk + 4) ^ x) * 8];
        }
        #pragma unroll
        for (int n = 0; n < FN; ++n) {
            const int row = wn * WAVE_N + n * 16 + lrow;
            const int x = row & 7;
            bh[n] = *(const bf16x8*)&BsP[row * 64 + ((lk)     ^ x) * 8];
            bl[n] = *(const bf16x8*)&BsP[row * 64 + ((lk + 4) ^ x) * 8];
        }
        #pragma unroll
        for (int m = 0; m < FM; ++m)
            #pragma unroll
            for (int n = 0; n < FN; ++n) {
                acc[m][n] = __builtin_amdgcn_mfma_f32_16x16x32_bf16(ah[m], bh[n], acc[m][n], 0, 0, 0);
                acc[m][n] = __builtin_amdgcn_mfma_f32_16x16x32_bf16(al[m], bh[n], acc[m][n], 0, 0, 0);
                acc[m][n] = __builtin_amdgcn_mfma_f32_16x16x32_bf16(ah[m], bl[n], acc[m][n], 0, 0, 0);
            }
    };

    auto wait_nld = [&]() {
        if constexpr (NLD == 8)      asm volatile("s_waitcnt vmcnt(8)" ::: "memory");
        else if constexpr (NLD == 6) asm volatile("s_waitcnt vmcnt(6)" ::: "memory");
        else                         asm volatile("s_waitcnt vmcnt(0)" ::: "memory");
    };

    stage(As0, Bs0, 0);

    #pragma unroll 1
    for (int ks = 0; ks < 30; ks += 2) {
        stage(As1, Bs1, ks + 1);
        wait_nld();
        __builtin_amdgcn_s_barrier();
        __builtin_amdgcn_sched_barrier(0);
        compute(As0, Bs0);
        __builtin_amdgcn_s_barrier();

        stage(As0, Bs0, ks + 2);
        wait_nld();
        __builtin_amdgcn_s_barrier();
        __builtin_amdgcn_sched_barrier(0);
        compute(As1, Bs1);
        __builtin_amdgcn_s_barrier();
    }
    stage(As1, Bs1, 31);
    wait_nld();
    __builtin_amdgcn_s_barrier();
    __builtin_amdgcn_sched_barrier(0);
    compute(As0, Bs0);
    __builtin_amdgcn_s_barrier();

    asm volatile("s_waitcnt vmcnt(0)" ::: "memory");
    __builtin_amdgcn_s_barrier();
    __builtin_amdgcn_sched_barrier(0);
    compute(As1, Bs1);

    // C/D layout: col = lane&15, row = (lane>>4)*4 + j
    #pragma unroll
    for (int m = 0; m < FM; ++m)
        #pragma unroll
        for (int j = 0; j < 4; ++j) {
            const int row = bm + wm * WAVE_M + m * 16 + lk * 4 + j;
            float* cr = C + (size_t)row * N + bn + wn * WAVE_N + lrow;
            #pragma unroll
            for (int n = 0; n < FN; ++n)
                cr[n * 16] = acc[m][n][j];
        }
}

// ---------------------------------------------------------------------------
// Attention: ONE THREAD per (b, h, query i) — serial in-register reductions,
// zero cross-lane ops. Fast-math; fuses hi/lo bf16 expansion for stage C.
// ---------------------------------------------------------------------------
__global__ __launch_bounds__(256) void attn_kernel(
    const float* __restrict__ Q, const float* __restrict__ Kp, const float* __restrict__ Vp,
    const int* __restrict__ mask, const float* __restrict__ s_v, const float* __restrict__ s_r,
    ushort_t* __restrict__ Oe)
{
    const int gid = blockIdx.x * 256 + threadIdx.x;   // 65536 threads
    const int i = gid % T_SZ;
    const int h = (gid / T_SZ) % NUM_HEADS;
    const int b = gid / (T_SZ * NUM_HEADS);

    const float w = __expf(s_v[h]) + 1.0f;
    const float r = __expf(s_r[h]) + 1.0f;
    const float inv_w = frcp(w);

    const size_t rowbase = (size_t)(b * T_SZ) * D_MODEL + h * HEAD_DIM;
    const float4* qrow = (const float4*)(Q + rowbase + (size_t)i * D_MODEL);

    float qq = 0.0f;
    #pragma unroll
    for (int g = 0; g < 16; ++g) {
        float4 q4 = qrow[g];
        qq = fmaf(q4.x, q4.x, fmaf(q4.y, q4.y, fmaf(q4.z, q4.z, fmaf(q4.w, q4.w, qq))));
    }
    const float qinv = frcp(fmaxf(sqrtf(qq), EPS));

    int jmin = i - (int)ceilf(w) + 1;
    if (jmin < 0) jmin = 0;

    float4 o[16];
    #pragma unroll
    for (int g = 0; g < 16; ++g) o[g] = make_float4(0.f, 0.f, 0.f, 0.f);

    for (int j = jmin; j <= i; ++j) {
        const float rel = (float)(j - i);
        if (!(rel > -w)) continue;
        const float4* krow = (const float4*)(Kp + rowbase + (size_t)j * D_MODEL);
        const float4* vrow = (const float4*)(Vp + rowbase + (size_t)j * D_MODEL);

        float kk = 0.0f, qk = 0.0f, vv = 0.0f;
        #pragma unroll
        for (int g = 0; g < 16; ++g) {
            float4 k4 = krow[g];
            float4 q4 = qrow[g];
            float4 v4 = vrow[g];
            kk = fmaf(k4.x, k4.x, fmaf(k4.y, k4.y, fmaf(k4.z, k4.z, fmaf(k4.w, k4.w, kk))));
            qk = fmaf(q4.x, k4.x, fmaf(q4.y, k4.y, fmaf(q4.z, k4.z, fmaf(q4.w, k4.w, qk))));
            vv = fmaf(v4.x, v4.x, fmaf(v4.y, v4.y, fmaf(v4.z, v4.z, fmaf(v4.w, v4.w, vv))));
        }
        const float kinv = frcp(fmaxf(sqrtf(kk), EPS));
        const float vinv = frcp(fmaxf(sqrtf(vv), EPS));
        const float sim = qk * qinv * kinv;

        const float cm = 0.5f * (__cosf((float)M_PI * rel * inv_w) + 1.0f);
        const float a1 = fmaxf(1.0f - r * (1.0f - sim), 0.0f);
        float alpha = a1 * a1 * cm;
        if (mask[b * T_SZ + j] != 0) alpha = 0.0f;
        const float av = alpha * vinv;

        #pragma unroll
        for (int g = 0; g < 16; ++g) {
            float4 v4 = vrow[g];
            o[g].x = fmaf(av, v4.x, o[g].x);
            o[g].y = fmaf(av, v4.y, o[g].y);
            o[g].z = fmaf(av, v4.z, o[g].z);
            o[g].w = fmaf(av, v4.w, o[g].w);
        }
    }

    float oo = 0.0f;
    #pragma unroll
    for (int g = 0; g < 16; ++g)
        oo = fmaf(o[g].x, o[g].x, fmaf(o[g].y, o[g].y, fmaf(o[g].z, o[g].z, fmaf(o[g].w, o[g].w, oo))));
    const float n = sqrtf(oo);
    const float th = 1.0f - 2.0f * frcp(__expf(2.0f * n) + 1.0f);
    const float sc = th * frcp(n + EPS);

    const int row = b * T_SZ + i;
    ushort_t* orow = Oe + (size_t)row * KEXP;
    #pragma unroll
    for (int g = 0; g < 16; ++g) {
        const int kg = h * HEAD_DIM + g * 4;
        ushort_t* dst = orow + (kg >> 5) * 64 + (kg & 31);
        float x0 = o[g].x * sc, x1 = o[g].y * sc, x2 = o[g].z * sc, x3 = o[g].w * sc;
        ushort_t h0 = f2bf(x0), h1 = f2bf(x1), h2 = f2bf(x2), h3 = f2bf(x3);
        ushort_t l0 = f2bf(x0 - bf2f(h0)), l1 = f2bf(x1 - bf2f(h1));
        ushort_t l2 = f2bf(x2 - bf2f(h2)), l3 = f2bf(x3 - bf2f(h3));
        uint2 hw, lw;
        hw.x = (unsigned)h0 | ((unsigned)h1 << 16);
        hw.y = (unsigned)h2 | ((unsigned)h3 << 16);
        lw.x = (unsigned)l0 | ((unsigned)l1 << 16);
        lw.y = (unsigned)l2 | ((unsigned)l3 << 16);
        *(uint2*)dst        = hw;
        *(uint2*)(dst + 32) = lw;
    }
}

// ---------------------------------------------------------------------------
extern "C" void kernel_launch(void* const* d_in, const int* in_sizes, int n_in,
                              void* d_out, int out_size, void* d_ws, size_t ws_size,
                              hipStream_t stream) {
    const float* query = (const float*)d_in[0];
    const float* key   = (const float*)d_in[1];
    const float* value = (const float*)d_in[2];
    const int*   mask  = (const int*)d_in[3];
    const float* Wq    = (const float*)d_in[4];
    const float* Wk    = (const float*)d_in[5];
    const float* Wv    = (const float*)d_in[6];
    const float* Wo    = (const float*)d_in[7];
    const float* s_v   = (const float*)d_in[8];
    const float* s_r   = (const float*)d_in[9];
    float* out = (float*)d_out;

    const int M = B_SZ * T_SZ;                 // 4096
    const size_t MB = 1u << 20;

    char* ws = (char*)d_ws;
    ushort_t* qe  = (ushort_t*)(ws + 0 * MB);    // 16 MB each
    ushort_t* ke  = (ushort_t*)(ws + 16 * MB);
    ushort_t* ve  = (ushort_t*)(ws + 32 * MB);
    ushort_t* wqe = (ushort_t*)(ws + 48 * MB);   // 4 MB each
    ushort_t* wke = (ushort_t*)(ws + 52 * MB);
    ushort_t* wve = (ushort_t*)(ws + 56 * MB);
    ushort_t* woe = (ushort_t*)(ws + 60 * MB);
    float*    qp  = (float*)(ws + 64 * MB);      // 16 MB each fp32
    float*    kp  = (float*)(ws + 80 * MB);
    float*    vp  = (float*)(ws + 96 * MB);
    ushort_t* aoe = qe;                          // reuse qe after stage A

    // Stage 0: expand all 7 fp32 tensors to hi/lo bf16 planes
    hipLaunchKernelGGL(expand7, dim3(1024, 1, 7), dim3(256), 0, stream,
                       query, key, value, Wq, Wk, Wv, Wo,
                       qe, ke, ve, wqe, wke, wve, woe);

    // Stage A: Q/K/V projections — stage-C-proven dbuf structure,
    // 128x64 tiles, 1536 blocks (%8==0), NLD=6, 48 KB LDS
    hipLaunchKernelGGL((gemm_db3<64, 4, 1>), dim3(D_MODEL / 64, M / 128, 3), dim3(256), 0, stream,
                       qe, wqe, qp,
                       ke, wke, kp,
                       ve, wve, vp,
                       M, D_MODEL);

    // Stage B: thread-serial screening attention
    const int total_threads = B_SZ * NUM_HEADS * T_SZ;   // 65536
    hipLaunchKernelGGL(attn_kernel, dim3(total_threads / 256), dim3(256), 0, stream,
                       qp, kp, vp, mask, s_v, s_r, aoe);

    // Stage C: output projection, same structure, 512 blocks
    hipLaunchKernelGGL((gemm_db3<64, 4, 1>), dim3(D_MODEL / 64, M / 128, 1), dim3(256), 0, stream,
                       aoe, woe, out,
                       aoe, woe, out,
                       aoe, woe, out,
                       M, D_MODEL);
}

// Round 15
// 158.708 us; speedup vs baseline: 1.0279x; 1.0279x over previous
//
#include <hip/hip_runtime.h>
#include <math.h>

#define D_MODEL 1024
#define NUM_HEADS 16
#define HEAD_DIM 64
#define EPS 1e-8f
#define B_SZ 2
#define T_SZ 2048
#define KEXP 2048          // expanded K (hi+lo interleaved per 32-chunk)

typedef unsigned short ushort_t;
typedef __attribute__((ext_vector_type(8))) short bf16x8;
typedef __attribute__((ext_vector_type(4))) float f32x4;

// float -> bf16 round-to-nearest-even
__device__ __forceinline__ ushort_t f2bf(float f) {
    unsigned u = __float_as_uint(f);
    unsigned r = (u + 0x7FFFu + ((u >> 16) & 1u)) >> 16;
    return (ushort_t)r;
}
__device__ __forceinline__ float bf2f(ushort_t h) {
    return __uint_as_float(((unsigned)h) << 16);
}
__device__ __forceinline__ float frcp(float x) { return __builtin_amdgcn_rcpf(x); }

__device__ __forceinline__ void gload_lds16(const ushort_t* g, ushort_t* l) {
    __builtin_amdgcn_global_load_lds(
        (const __attribute__((address_space(1))) unsigned int*)g,
        (__attribute__((address_space(3))) unsigned int*)l, 16, 0, 0);
}

// ---------------------------------------------------------------------------
// Expand fp32 [rows][1024] -> bf16 [rows][2048]; per 32-k chunk: 32 hi, 32 lo.
// ---------------------------------------------------------------------------
__global__ __launch_bounds__(256) void expand7(
    const float* q, const float* k, const float* v,
    const float* wq, const float* wk, const float* wv, const float* wo,
    ushort_t* qe, ushort_t* ke, ushort_t* ve,
    ushort_t* wqe, ushort_t* wke, ushort_t* wve, ushort_t* woe)
{
    const float* in; ushort_t* out; int rows;
    switch (blockIdx.z) {
        case 0: in = q;  out = qe;  rows = 4096; break;
        case 1: in = k;  out = ke;  rows = 4096; break;
        case 2: in = v;  out = ve;  rows = 4096; break;
        case 3: in = wq; out = wqe; rows = 1024; break;
        case 4: in = wk; out = wke; rows = 1024; break;
        case 5: in = wv; out = wve; rows = 1024; break;
        default: in = wo; out = woe; rows = 1024; break;
    }
    const int gid = blockIdx.x * 256 + threadIdx.x;
    const int total = rows * 1024;
    for (int e = gid * 8; e < total; e += 1024 * 256 * 8) {
        const int row = e >> 10;
        const int kk = e & 1023;

        float x[8];
        *(float4*)&x[0] = *(const float4*)&in[(size_t)row * 1024 + kk];
        *(float4*)&x[4] = *(const float4*)&in[(size_t)row * 1024 + kk + 4];

        union { ushort_t s[8]; uint4 u; } hi, lo;
        #pragma unroll
        for (int i = 0; i < 8; ++i) {
            ushort_t h = f2bf(x[i]);
            hi.s[i] = h;
            lo.s[i] = f2bf(x[i] - bf2f(h));
        }
        ushort_t* dst = out + (size_t)row * KEXP + (kk >> 5) * 64 + (kk & 31);
        *(uint4*)dst        = hi.u;
        *(uint4*)(dst + 32) = lo.u;
    }
}

// ---------------------------------------------------------------------------
// Stage A: R13-proven split-bf16 MFMA GEMM (NT). Single-buffer 2-phase,
// 128x128 tiles, 4 waves (2x2), 16x16x32, 3 MFMAs (hh, lh, hl) per pair.
// Best of 6 bracketed K-loop structures (dbuf/8-wave/32x32/convert-fused/
// 64-tile-dbuf all regressed). LDS rows 128B, XOR slot-swizzle s^(row&7);
// bijective XCD swizzle.
// ---------------------------------------------------------------------------
__global__ __launch_bounds__(256) void gemm_sb3(
    const ushort_t* A0, const ushort_t* B0, float* C0,
    const ushort_t* A1, const ushort_t* B1, float* C1,
    const ushort_t* A2, const ushort_t* B2, float* C2,
    int M, int N)
{
    constexpr int BM = 128, BN = 128, WAVES_N = 2;
    constexpr int WAVE_M = 64, WAVE_N = 64, FM = 4, FN = 4;

    const int gx = gridDim.x, gy = gridDim.y;
    const int nwg = gx * gy * gridDim.z;
    const int lid = blockIdx.x + gx * (blockIdx.y + gy * blockIdx.z);
    const int cpx = nwg >> 3;
    const int swz = (lid & 7) * cpx + (lid >> 3);
    const int bz  = swz / (gx * gy);
    const int rem = swz - bz * gx * gy;
    const int by  = rem / gx;
    const int bx  = rem - by * gx;

    const ushort_t* Ae; const ushort_t* Be; float* C;
    if (bz == 0)      { Ae = A0; Be = B0; C = C0; }
    else if (bz == 1) { Ae = A1; Be = B1; C = C1; }
    else              { Ae = A2; Be = B2; C = C2; }

    __shared__ __align__(16) ushort_t As[BM * 64];
    __shared__ __align__(16) ushort_t Bs[BN * 64];

    const int tid = threadIdx.x;
    const int bm = by * BM;
    const int bn = bx * BN;

    const int rr = tid >> 3;      // 0..31
    const int p  = tid & 7;

    const int wid  = tid >> 6;
    const int wm   = wid / WAVES_N;
    const int wn   = wid % WAVES_N;
    const int lane = tid & 63;
    const int lrow = lane & 15;
    const int lk   = lane >> 4;

    f32x4 acc[FM][FN] = {};

    for (int ks = 0; ks < 32; ++ks) {
        const int kb = ks * 64;
        #pragma unroll
        for (int r = 0; r < 4; ++r) {
            const int row = r * 32 + rr;
            const int s = p ^ (row & 7);
            gload_lds16(Ae + (size_t)(bm + row) * KEXP + kb + s * 8,
                        &As[row * 64 + p * 8]);
        }
        #pragma unroll
        for (int r = 0; r < 4; ++r) {
            const int row = r * 32 + rr;
            const int s = p ^ (row & 7);
            gload_lds16(Be + (size_t)(bn + row) * KEXP + kb + s * 8,
                        &Bs[row * 64 + p * 8]);
        }
        __syncthreads();

        bf16x8 ah[FM], al[FM], bh[FN], bl[FN];
        #pragma unroll
        for (int m = 0; m < FM; ++m) {
            const int row = wm * WAVE_M + m * 16 + lrow;
            const int x = row & 7;
            ah[m] = *(const bf16x8*)&As[row * 64 + ((lk)     ^ x) * 8];
            al[m] = *(const bf16x8*)&As[row * 64 + ((lk + 4) ^ x) * 8];
        }
        #pragma unroll
        for (int n = 0; n < FN; ++n) {
            const int row = wn * WAVE_N + n * 16 + lrow;
            const int x = row & 7;
            bh[n] = *(const bf16x8*)&Bs[row * 64 + ((lk)     ^ x) * 8];
            bl[n] = *(const bf16x8*)&Bs[row * 64 + ((lk + 4) ^ x) * 8];
        }
        #pragma unroll
        for (int m = 0; m < FM; ++m)
            #pragma unroll
            for (int n = 0; n < FN; ++n) {
                acc[m][n] = __builtin_amdgcn_mfma_f32_16x16x32_bf16(ah[m], bh[n], acc[m][n], 0, 0, 0);
                acc[m][n] = __builtin_amdgcn_mfma_f32_16x16x32_bf16(al[m], bh[n], acc[m][n], 0, 0, 0);
                acc[m][n] = __builtin_amdgcn_mfma_f32_16x16x32_bf16(ah[m], bl[n], acc[m][n], 0, 0, 0);
            }
        __syncthreads();
    }

    // C/D layout: col = lane&15, row = (lane>>4)*4 + j
    #pragma unroll
    for (int m = 0; m < FM; ++m)
        #pragma unroll
        for (int j = 0; j < 4; ++j) {
            const int row = bm + wm * WAVE_M + m * 16 + lk * 4 + j;
            float* cr = C + (size_t)row * N + bn + wn * WAVE_N + lrow;
            #pragma unroll
            for (int n = 0; n < FN; ++n)
                cr[n * 16] = acc[m][n][j];
        }
}

// ---------------------------------------------------------------------------
// Stage C: R7-proven split-bf16 GEMM, dbuf + counted vmcnt (T4), BN=64.
// ---------------------------------------------------------------------------
template<int BN, int WAVES_M, int WAVES_N>
__global__ __launch_bounds__(256) void gemm_db(
    const ushort_t* A0, const ushort_t* B0, float* C0, int M, int N)
{
    constexpr int BM = 128;
    constexpr int WAVE_M = BM / WAVES_M;
    constexpr int WAVE_N = BN / WAVES_N;
    constexpr int FM = WAVE_M / 16;
    constexpr int FN = WAVE_N / 16;
    constexpr int NLD = BM / 32 + BN / 32;

    const int gx = gridDim.x;
    const int nwg = gx * gridDim.y;
    const int lid = blockIdx.x + gx * blockIdx.y;
    const int cpx = nwg >> 3;
    const int swz = (lid & 7) * cpx + (lid >> 3);
    const int by  = swz / gx;
    const int bx  = swz - by * gx;

    const ushort_t* Ae = A0; const ushort_t* Be = B0; float* C = C0;

    __shared__ __align__(16) ushort_t As0[BM * 64];
    __shared__ __align__(16) ushort_t As1[BM * 64];
    __shared__ __align__(16) ushort_t Bs0[BN * 64];
    __shared__ __align__(16) ushort_t Bs1[BN * 64];

    const int tid = threadIdx.x;
    const int bm = by * BM;
    const int bn = bx * BN;

    const int rr = tid >> 3;
    const int p  = tid & 7;

    const int wid  = tid >> 6;
    const int wm   = wid / WAVES_N;
    const int wn   = wid % WAVES_N;
    const int lane = tid & 63;
    const int lrow = lane & 15;
    const int lk   = lane >> 4;

    f32x4 acc[FM][FN] = {};

    auto stage = [&](ushort_t* AsP, ushort_t* BsP, int ks) {
        const int kb = ks * 64;
        #pragma unroll
        for (int r = 0; r < BM / 32; ++r) {
            const int row = r * 32 + rr;
            const int s = p ^ (row & 7);
            gload_lds16(Ae + (size_t)(bm + row) * KEXP + kb + s * 8,
                        &AsP[row * 64 + p * 8]);
        }
        #pragma unroll
        for (int r = 0; r < BN / 32; ++r) {
            const int row = r * 32 + rr;
            const int s = p ^ (row & 7);
            gload_lds16(Be + (size_t)(bn + row) * KEXP + kb + s * 8,
                        &BsP[row * 64 + p * 8]);
        }
    };

    auto compute = [&](const ushort_t* AsP, const ushort_t* BsP) {
        bf16x8 ah[FM], al[FM], bh[FN], bl[FN];
        #pragma unroll
        for (int m = 0; m < FM; ++m) {
            const int row = wm * WAVE_M + m * 16 + lrow;
            const int x = row & 7;
            ah[m] = *(const bf16x8*)&AsP[row * 64 + ((lk)     ^ x) * 8];
            al[m] = *(const bf16x8*)&AsP[row * 64 + ((lk + 4) ^ x) * 8];
        }
        #pragma unroll
        for (int n = 0; n < FN; ++n) {
            const int row = wn * WAVE_N + n * 16 + lrow;
            const int x = row & 7;
            bh[n] = *(const bf16x8*)&BsP[row * 64 + ((lk)     ^ x) * 8];
            bl[n] = *(const bf16x8*)&BsP[row * 64 + ((lk + 4) ^ x) * 8];
        }
        #pragma unroll
        for (int m = 0; m < FM; ++m)
            #pragma unroll
            for (int n = 0; n < FN; ++n) {
                acc[m][n] = __builtin_amdgcn_mfma_f32_16x16x32_bf16(ah[m], bh[n], acc[m][n], 0, 0, 0);
                acc[m][n] = __builtin_amdgcn_mfma_f32_16x16x32_bf16(al[m], bh[n], acc[m][n], 0, 0, 0);
                acc[m][n] = __builtin_amdgcn_mfma_f32_16x16x32_bf16(ah[m], bl[n], acc[m][n], 0, 0, 0);
            }
    };

    auto wait_nld = [&]() {
        if constexpr (NLD == 8)      asm volatile("s_waitcnt vmcnt(8)" ::: "memory");
        else if constexpr (NLD == 6) asm volatile("s_waitcnt vmcnt(6)" ::: "memory");
        else                         asm volatile("s_waitcnt vmcnt(0)" ::: "memory");
    };

    stage(As0, Bs0, 0);

    #pragma unroll 1
    for (int ks = 0; ks < 30; ks += 2) {
        stage(As1, Bs1, ks + 1);
        wait_nld();
        __builtin_amdgcn_s_barrier();
        __builtin_amdgcn_sched_barrier(0);
        compute(As0, Bs0);
        __builtin_amdgcn_s_barrier();

        stage(As0, Bs0, ks + 2);
        wait_nld();
        __builtin_amdgcn_s_barrier();
        __builtin_amdgcn_sched_barrier(0);
        compute(As1, Bs1);
        __builtin_amdgcn_s_barrier();
    }
    stage(As1, Bs1, 31);
    wait_nld();
    __builtin_amdgcn_s_barrier();
    __builtin_amdgcn_sched_barrier(0);
    compute(As0, Bs0);
    __builtin_amdgcn_s_barrier();

    asm volatile("s_waitcnt vmcnt(0)" ::: "memory");
    __builtin_amdgcn_s_barrier();
    __builtin_amdgcn_sched_barrier(0);
    compute(As1, Bs1);

    #pragma unroll
    for (int m = 0; m < FM; ++m)
        #pragma unroll
        for (int j = 0; j < 4; ++j) {
            const int row = bm + wm * WAVE_M + m * 16 + lk * 4 + j;
            float* cr = C + (size_t)row * N + bn + wn * WAVE_N + lrow;
            #pragma unroll
            for (int n = 0; n < FN; ++n)
                cr[n * 16] = acc[m][n][j];
        }
}

// ---------------------------------------------------------------------------
// Attention: ONE THREAD per (b, h, query i) — serial in-register reductions,
// zero cross-lane ops. Fast-math; fuses hi/lo bf16 expansion for stage C.
// ---------------------------------------------------------------------------
__global__ __launch_bounds__(256) void attn_kernel(
    const float* __restrict__ Q, const float* __restrict__ Kp, const float* __restrict__ Vp,
    const int* __restrict__ mask, const float* __restrict__ s_v, const float* __restrict__ s_r,
    ushort_t* __restrict__ Oe)
{
    const int gid = blockIdx.x * 256 + threadIdx.x;   // 65536 threads
    const int i = gid % T_SZ;
    const int h = (gid / T_SZ) % NUM_HEADS;
    const int b = gid / (T_SZ * NUM_HEADS);

    const float w = __expf(s_v[h]) + 1.0f;
    const float r = __expf(s_r[h]) + 1.0f;
    const float inv_w = frcp(w);

    const size_t rowbase = (size_t)(b * T_SZ) * D_MODEL + h * HEAD_DIM;
    const float4* qrow = (const float4*)(Q + rowbase + (size_t)i * D_MODEL);

    float qq = 0.0f;
    #pragma unroll
    for (int g = 0; g < 16; ++g) {
        float4 q4 = qrow[g];
        qq = fmaf(q4.x, q4.x, fmaf(q4.y, q4.y, fmaf(q4.z, q4.z, fmaf(q4.w, q4.w, qq))));
    }
    const float qinv = frcp(fmaxf(sqrtf(qq), EPS));

    int jmin = i - (int)ceilf(w) + 1;
    if (jmin < 0) jmin = 0;

    float4 o[16];
    #pragma unroll
    for (int g = 0; g < 16; ++g) o[g] = make_float4(0.f, 0.f, 0.f, 0.f);

    for (int j = jmin; j <= i; ++j) {
        const float rel = (float)(j - i);
        if (!(rel > -w)) continue;
        const float4* krow = (const float4*)(Kp + rowbase + (size_t)j * D_MODEL);
        const float4* vrow = (const float4*)(Vp + rowbase + (size_t)j * D_MODEL);

        float kk = 0.0f, qk = 0.0f, vv = 0.0f;
        #pragma unroll
        for (int g = 0; g < 16; ++g) {
            float4 k4 = krow[g];
            float4 q4 = qrow[g];
            float4 v4 = vrow[g];
            kk = fmaf(k4.x, k4.x, fmaf(k4.y, k4.y, fmaf(k4.z, k4.z, fmaf(k4.w, k4.w, kk))));
            qk = fmaf(q4.x, k4.x, fmaf(q4.y, k4.y, fmaf(q4.z, k4.z, fmaf(q4.w, k4.w, qk))));
            vv = fmaf(v4.x, v4.x, fmaf(v4.y, v4.y, fmaf(v4.z, v4.z, fmaf(v4.w, v4.w, vv))));
        }
        const float kinv = frcp(fmaxf(sqrtf(kk), EPS));
        const float vinv = frcp(fmaxf(sqrtf(vv), EPS));
        const float sim = qk * qinv * kinv;

        const float cm = 0.5f * (__cosf((float)M_PI * rel * inv_w) + 1.0f);
        const float a1 = fmaxf(1.0f - r * (1.0f - sim), 0.0f);
        float alpha = a1 * a1 * cm;
        if (mask[b * T_SZ + j] != 0) alpha = 0.0f;
        const float av = alpha * vinv;

        #pragma unroll
        for (int g = 0; g < 16; ++g) {
            float4 v4 = vrow[g];
            o[g].x = fmaf(av, v4.x, o[g].x);
            o[g].y = fmaf(av, v4.y, o[g].y);
            o[g].z = fmaf(av, v4.z, o[g].z);
            o[g].w = fmaf(av, v4.w, o[g].w);
        }
    }

    float oo = 0.0f;
    #pragma unroll
    for (int g = 0; g < 16; ++g)
        oo = fmaf(o[g].x, o[g].x, fmaf(o[g].y, o[g].y, fmaf(o[g].z, o[g].z, fmaf(o[g].w, o[g].w, oo))));
    const float n = sqrtf(oo);
    const float th = 1.0f - 2.0f * frcp(__expf(2.0f * n) + 1.0f);
    const float sc = th * frcp(n + EPS);

    const int row = b * T_SZ + i;
    ushort_t* orow = Oe + (size_t)row * KEXP;
    #pragma unroll
    for (int g = 0; g < 16; ++g) {
        const int kg = h * HEAD_DIM + g * 4;
        ushort_t* dst = orow + (kg >> 5) * 64 + (kg & 31);
        float x0 = o[g].x * sc, x1 = o[g].y * sc, x2 = o[g].z * sc, x3 = o[g].w * sc;
        ushort_t h0 = f2bf(x0), h1 = f2bf(x1), h2 = f2bf(x2), h3 = f2bf(x3);
        ushort_t l0 = f2bf(x0 - bf2f(h0)), l1 = f2bf(x1 - bf2f(h1));
        ushort_t l2 = f2bf(x2 - bf2f(h2)), l3 = f2bf(x3 - bf2f(h3));
        uint2 hw, lw;
        hw.x = (unsigned)h0 | ((unsigned)h1 << 16);
        hw.y = (unsigned)h2 | ((unsigned)h3 << 16);
        lw.x = (unsigned)l0 | ((unsigned)l1 << 16);
        lw.y = (unsigned)l2 | ((unsigned)l3 << 16);
        *(uint2*)dst        = hw;
        *(uint2*)(dst + 32) = lw;
    }
}

// ---------------------------------------------------------------------------
extern "C" void kernel_launch(void* const* d_in, const int* in_sizes, int n_in,
                              void* d_out, int out_size, void* d_ws, size_t ws_size,
                              hipStream_t stream) {
    const float* query = (const float*)d_in[0];
    const float* key   = (const float*)d_in[1];
    const float* value = (const float*)d_in[2];
    const int*   mask  = (const int*)d_in[3];
    const float* Wq    = (const float*)d_in[4];
    const float* Wk    = (const float*)d_in[5];
    const float* Wv    = (const float*)d_in[6];
    const float* Wo    = (const float*)d_in[7];
    const float* s_v   = (const float*)d_in[8];
    const float* s_r   = (const float*)d_in[9];
    float* out = (float*)d_out;

    const int M = B_SZ * T_SZ;                 // 4096
    const size_t MB = 1u << 20;

    char* ws = (char*)d_ws;
    ushort_t* qe  = (ushort_t*)(ws + 0 * MB);    // 16 MB each
    ushort_t* ke  = (ushort_t*)(ws + 16 * MB);
    ushort_t* ve  = (ushort_t*)(ws + 32 * MB);
    ushort_t* wqe = (ushort_t*)(ws + 48 * MB);   // 4 MB each
    ushort_t* wke = (ushort_t*)(ws + 52 * MB);
    ushort_t* wve = (ushort_t*)(ws + 56 * MB);
    ushort_t* woe = (ushort_t*)(ws + 60 * MB);
    float*    qp  = (float*)(ws + 64 * MB);      // 16 MB each fp32
    float*    kp  = (float*)(ws + 80 * MB);
    float*    vp  = (float*)(ws + 96 * MB);
    ushort_t* aoe = qe;                          // reuse qe after stage A

    // Stage 0: expand all 7 fp32 tensors to hi/lo bf16 planes
    hipLaunchKernelGGL(expand7, dim3(1024, 1, 7), dim3(256), 0, stream,
                       query, key, value, Wq, Wk, Wv, Wo,
                       qe, ke, ve, wqe, wke, wve, woe);

    // Stage A: Q/K/V projections (plain epilogue), 128x128 tiles, 768 blocks
    hipLaunchKernelGGL(gemm_sb3, dim3(D_MODEL / 128, M / 128, 3), dim3(256), 0, stream,
                       qe, wqe, qp,
                       ke, wke, kp,
                       ve, wve, vp,
                       M, D_MODEL);

    // Stage B: thread-serial screening attention (no cross-lane ops)
    const int total_threads = B_SZ * NUM_HEADS * T_SZ;   // 65536
    hipLaunchKernelGGL(attn_kernel, dim3(total_threads / 256), dim3(256), 0, stream,
                       qp, kp, vp, mask, s_v, s_r, aoe);

    // Stage C: output projection, 128x64 tiles, dbuf+counted vmcnt, 512 blocks
    hipLaunchKernelGGL((gemm_db<64, 4, 1>), dim3(D_MODEL / 64, M / 128, 1), dim3(256), 0, stream,
                       aoe, woe, out, M, D_MODEL);
}